// Round 6
// baseline (254.101 us; speedup 1.0000x reference)
//
#include <hip/hip_runtime.h>
#include <stdint.h>

// LinearWithLoRA: out = x@W.T + b + 2.0*(x@A.T)@B.T   (out fp32 [8192,2048])
// x[8192,2048] f32, W[2048,2048] f32, b[2048] f32, A[16,2048] f32, B[2048,16] f32
//
// R6 changes vs R5 (post-mortem: in-loop P cost 16us due to wave-0-only 5th
// global_load_lds gating the barrier + extra Ps ds_read for all waves):
//  - P path A-fragment now read DIRECTLY from global per K-step by wc==0 waves
//    (Ab is 64KB -> L2-resident; 16B dwordx4/lane/step, symmetric wave load).
//  - Ps LDS tile and 5th gload removed (LDS back to 16KB).
//  - prep_cvt: 2 rows per block (load ILP), barrier kept (in-place hazard).

#define SCALING 2.0f

typedef __attribute__((ext_vector_type(8))) __bf16 bf16x8;
typedef __attribute__((ext_vector_type(4))) float f32x4;

static __device__ __forceinline__ unsigned short f2bf(float f) {
  union { float f; unsigned int u; } v; v.f = f;
  return (unsigned short)((v.u + 0x7FFFu + ((v.u >> 16) & 1u)) >> 16);
}

// ---- prep: in-place fp32 -> bf16 row convert (row = 2048 floats) ----
// 2 rows per block: x 8192 rows -> 4096 blocks, W 2048 -> 1024, A 16 -> 8.
__global__ __launch_bounds__(256) void prep_cvt(float* x, float* W, float* A) {
  const int bid = blockIdx.x;
  float* base; size_t row0;
  if (bid < 4096)      { base = x; row0 = (size_t)bid * 2; }
  else if (bid < 5120) { base = W; row0 = (size_t)(bid - 4096) * 2; }
  else                 { base = A; row0 = (size_t)(bid - 5120) * 2; }
  const int t = threadIdx.x;
  const float* s0 = base + row0 * 2048 + t * 8;
  const float* s1 = s0 + 2048;
  float4 v0 = *(const float4*)s0;
  float4 v1 = *(const float4*)(s0 + 4);
  float4 v2 = *(const float4*)s1;
  float4 v3 = *(const float4*)(s1 + 4);
  __syncthreads();   // all fp32 reads of both rows complete before any bf16 write
  union { unsigned short h[8]; uint4 v; } p0, p1;
  p0.h[0]=f2bf(v0.x); p0.h[1]=f2bf(v0.y); p0.h[2]=f2bf(v0.z); p0.h[3]=f2bf(v0.w);
  p0.h[4]=f2bf(v1.x); p0.h[5]=f2bf(v1.y); p0.h[6]=f2bf(v1.z); p0.h[7]=f2bf(v1.w);
  p1.h[0]=f2bf(v2.x); p1.h[1]=f2bf(v2.y); p1.h[2]=f2bf(v2.z); p1.h[3]=f2bf(v2.w);
  p1.h[4]=f2bf(v3.x); p1.h[5]=f2bf(v3.y); p1.h[6]=f2bf(v3.z); p1.h[7]=f2bf(v3.w);
  unsigned short* d = (unsigned short*)base + row0 * 4096 + t * 8;
  *(uint4*)d = p0.v;
  *(uint4*)(d + 4096) = p1.v;
}

// ---------------- main GEMM ----------------
#define GLOAD16(gp, lp)                                                        \
  __builtin_amdgcn_global_load_lds(                                            \
      (const __attribute__((address_space(1))) void*)(const void*)(gp),        \
      (__attribute__((address_space(3))) void*)(void*)(lp), 16, 0, 0)

__global__ __launch_bounds__(256) void gemm_lora(
    const unsigned short* __restrict__ Xb,   // bf16, pitch 4096 shorts
    const unsigned short* __restrict__ Wb,   // bf16, pitch 4096 shorts
    const unsigned short* __restrict__ Ab,   // bf16 lora_A, pitch 4096 shorts, 16 rows
    const float* __restrict__ lB,            // [2048][16] fp32
    const float* __restrict__ bias, float* __restrict__ out) {
  __shared__ unsigned short As[128 * 32];
  __shared__ unsigned short Bs[128 * 32];
  const int tid = threadIdx.x;
  const int lane = tid & 63;
  const int w = tid >> 6;
  const int wr = w >> 1, wc = w & 1;

  // XCD-chunked bijective blockIdx swizzle (grid=1024, 1024%8==0)
  const int bid = blockIdx.x;
  const int b2 = (bid & 7) * 128 + (bid >> 3);
  const int tn = b2 >> 6;   // 0..15
  const int tm = b2 & 63;   // 0..63
  const size_t row0 = (size_t)tm * 128;
  const size_t col0 = (size_t)tn * 128;

  // staging: wave w fills issues q0,q1 (16 rows x 32 cols = 1KB each) of A and B
  const int q0 = 2 * w, q1 = q0 + 1;
  const int rq = lane >> 2, p = lane & 3;
  const int rl0 = q0 * 16 + rq, rl1 = q1 * 16 + rq;
  const unsigned short* gA0 = Xb + (row0 + rl0) * 4096 + p * 8;
  const unsigned short* gA1 = Xb + (row0 + rl1) * 4096 + p * 8;
  const unsigned short* gB0 = Wb + (col0 + rl0) * 4096 + p * 8;
  const unsigned short* gB1 = Wb + (col0 + rl1) * 4096 + p * 8;
  unsigned short* lA0 = &As[q0 * 512];
  unsigned short* lA1 = &As[q1 * 512];
  unsigned short* lB0 = &Bs[q0 * 512];
  unsigned short* lB1 = &Bs[q1 * 512];

  // fragment read offsets: lane -> row fr within 16-row tile, k-group g
  const int fr = lane & 15, g = lane >> 4;
  int aidx[4], bidx[4];
  #pragma unroll
  for (int m = 0; m < 4; ++m) aidx[m] = (wr * 64 + m * 16 + fr) * 32 + g * 8;
  #pragma unroll
  for (int n = 0; n < 4; ++n) bidx[n] = (wc * 64 + n * 16 + fr) * 32 + g * 8;

  // P path: lane's lora_A row fragment source (row fr of Ab, 64KB L2-resident)
  const unsigned short* gPA = Ab + (size_t)fr * 4096 + g * 8;

  f32x4 acc[4][4];
  f32x4 accP[4];
  #pragma unroll
  for (int m = 0; m < 4; ++m) {
    accP[m] = f32x4{0.f, 0.f, 0.f, 0.f};
    #pragma unroll
    for (int n = 0; n < 4; ++n) acc[m][n] = f32x4{0.f, 0.f, 0.f, 0.f};
  }

  for (int s = 0; s < 64; ++s) {
    const int ko = s * 32;
    GLOAD16(gA0 + ko, lA0);
    GLOAD16(gA1 + ko, lA1);
    GLOAD16(gB0 + ko, lB0);
    GLOAD16(gB1 + ko, lB1);
    bf16x8 bvP;
    if (wc == 0) bvP = *(const bf16x8*)(gPA + ko);   // global, L2-hot
    __syncthreads();   // compiler drains vmcnt before s_barrier
    bf16x8 av[4], bv[4];
    #pragma unroll
    for (int m = 0; m < 4; ++m) av[m] = *(const bf16x8*)&As[aidx[m]];
    #pragma unroll
    for (int n = 0; n < 4; ++n) bv[n] = *(const bf16x8*)&Bs[bidx[n]];
    #pragma unroll
    for (int m = 0; m < 4; ++m)
      #pragma unroll
      for (int n = 0; n < 4; ++n)
        acc[m][n] = __builtin_amdgcn_mfma_f32_16x16x32_bf16(av[m], bv[n], acc[m][n], 0, 0, 0);
    if (wc == 0) {
      #pragma unroll
      for (int m = 0; m < 4; ++m)
        accP[m] = __builtin_amdgcn_mfma_f32_16x16x32_bf16(av[m], bvP, accP[m], 0, 0, 0);
    }
    __syncthreads();
  }

  // ---- LoRA finish: P (x2) -> LDS; lora_B -> bf16 in Bs; one extra K-step ----
  float* P_lds = (float*)As;   // 128 rows x 16 cols fp32 = 8KB, exact As reuse
  if (wc == 0) {
    #pragma unroll
    for (int m = 0; m < 4; ++m)
      #pragma unroll
      for (int j = 0; j < 4; ++j) {
        const int row = wr * 64 + m * 16 + (lane >> 4) * 4 + j;  // C/D: col=lane&15
        P_lds[row * 16 + fr] = SCALING * accP[m][j];
      }
  }
  {
    const int row = tid >> 1, h = tid & 1;   // stage lora_B rows col0..col0+127
    const float* bp = lB + (size_t)(col0 + row) * 16 + h * 8;
    float4 b0 = *(const float4*)bp, b1 = *(const float4*)(bp + 4);
    union { unsigned short hh[8]; uint4 v; } pb;
    pb.hh[0]=f2bf(b0.x); pb.hh[1]=f2bf(b0.y); pb.hh[2]=f2bf(b0.z); pb.hh[3]=f2bf(b0.w);
    pb.hh[4]=f2bf(b1.x); pb.hh[5]=f2bf(b1.y); pb.hh[6]=f2bf(b1.z); pb.hh[7]=f2bf(b1.w);
    *(uint4*)&Bs[row * 32 + h * 8] = pb.v;
    uint4 z; z.x = z.y = z.z = z.w = 0u;
    *(uint4*)&Bs[row * 32 + 16 + h * 8] = z;   // zero pad k=16..31
  }
  __syncthreads();

  {
    bf16x8 av2[4], bv2[4];
    #pragma unroll
    for (int m = 0; m < 4; ++m) {
      union { unsigned short hh[8]; bf16x8 v; } pa;
      if (g < 2) {
        const float* pr = &P_lds[(wr * 64 + m * 16 + fr) * 16 + g * 8];
        #pragma unroll
        for (int jj = 0; jj < 8; ++jj) pa.hh[jj] = f2bf(pr[jj]);
      } else {
        #pragma unroll
        for (int jj = 0; jj < 8; ++jj) pa.hh[jj] = 0;
      }
      av2[m] = pa.v;
    }
    #pragma unroll
    for (int n = 0; n < 4; ++n) bv2[n] = *(const bf16x8*)&Bs[bidx[n]];
    #pragma unroll
    for (int m = 0; m < 4; ++m)
      #pragma unroll
      for (int n = 0; n < 4; ++n)
        acc[m][n] = __builtin_amdgcn_mfma_f32_16x16x32_bf16(av2[m], bv2[n], acc[m][n], 0, 0, 0);
  }

  // ---- epilogue: + bias, FP32 store. C/D: col=lane&15, row=(lane>>4)*4+j ----
  #pragma unroll
  for (int n = 0; n < 4; ++n) {
    const int gn = (int)col0 + wc * 64 + n * 16 + fr;
    const float bvs = bias[gn];
    #pragma unroll
    for (int m = 0; m < 4; ++m) {
      const int gm0 = (int)row0 + wr * 64 + m * 16 + g * 4;
      #pragma unroll
      for (int j = 0; j < 4; ++j) {
        out[(size_t)(gm0 + j) * 2048 + gn] = acc[m][n][j] + bvs;
      }
    }
  }
}

extern "C" void kernel_launch(void* const* d_in, const int* in_sizes, int n_in,
                              void* d_out, int out_size, void* d_ws, size_t ws_size,
                              hipStream_t stream) {
  float* x  = (float*)d_in[0];
  float* W  = (float*)d_in[1];
  const float* b  = (const float*)d_in[2];
  float* lA = (float*)d_in[3];
  const float* lB = (const float*)d_in[4];
  float* out = (float*)d_out;
  (void)d_ws; (void)ws_size;

  prep_cvt<<<5128, 256, 0, stream>>>(x, W, lA);
  gemm_lora<<<1024, 256, 0, stream>>>((const unsigned short*)x, (const unsigned short*)W,
                                      (const unsigned short*)lA, lB, b, out);
}